// Round 2
// 1967.776 us; speedup vs baseline: 16.0649x; 16.0649x over previous
//
#include <hip/hip_runtime.h>
#include <stdint.h>

static constexpr int Vv = 32000, Dd = 512, Ss = 2048, Bx = 2, Lx = 6, Hx = 8, Fx = 2048;
static constexpr int Mx = Bx * Ss;   // 4096 token rows
static constexpr int DhX = 64;

typedef __bf16 bf16x8 __attribute__((ext_vector_type(8)));
typedef float f32x4 __attribute__((ext_vector_type(4)));

__device__ __forceinline__ unsigned short f2bf(float f) {
  union { float f; unsigned u; } v; v.f = f;
  unsigned r = v.u + 0x7FFFu + ((v.u >> 16) & 1u);   // RNE
  return (unsigned short)(r >> 16);
}

__device__ __forceinline__ void async_load16(const void* g, void* l) {
  __builtin_amdgcn_global_load_lds((__attribute__((address_space(1))) void*)g,
                                   (__attribute__((address_space(3))) void*)l, 16, 0, 0);
}

// ---------------- transpose + fp32->bf16 convert: out[c][r] = in[r][c] ----------------
__global__ void transpose_kernel(const float* in, unsigned short* out,
                                 int R, int C, long inL, long outL) {
  __shared__ float t[32][33];
  const float* inp = in + (size_t)blockIdx.z * inL;
  unsigned short* outp = out + (size_t)blockIdx.z * outL;
  int c0 = blockIdx.x * 32, r0 = blockIdx.y * 32;
  for (int i = threadIdx.y; i < 32; i += 8)
    t[i][threadIdx.x] = inp[(size_t)(r0 + i) * C + c0 + threadIdx.x];
  __syncthreads();
  for (int i = threadIdx.y; i < 32; i += 8)
    outp[(size_t)(c0 + i) * R + r0 + threadIdx.x] = f2bf(t[threadIdx.x][i]);
}

// ---------------- embedding + positional encoding ----------------
__global__ void embed_kernel(const int* x, const float* emb, const float* pe,
                             float* h, unsigned short* h_bf) {
  int idx = blockIdx.x * 256 + threadIdx.x;           // < Mx*Dd
  int row = idx >> 9, d = idx & 511;
  int s = row & (Ss - 1);
  float v = emb[(size_t)x[row] * Dd + d] + pe[(size_t)s * Dd + d];
  h[idx] = v;
  h_bf[idx] = f2bf(v);
}

// ---------------- bf16 MFMA GEMM: C[M,N] = A[M,K] @ Bt[N,K]^T (+bias, +relu) ----------
// 128x128 tile, BK=32, 256 threads (4 waves in 2x2), global_load_lds width=16 staging.
__global__ __launch_bounds__(256) void gemm_kernel(
    const unsigned short* __restrict__ A, const unsigned short* __restrict__ Bt,
    const float* __restrict__ bias, float* outF, unsigned short* outB,
    int M, int N, int K, int relu)
{
  __shared__ __align__(16) unsigned short As[128 * 32];
  __shared__ __align__(16) unsigned short Bs[128 * 32];
  const int tid = threadIdx.x;
  const int lane = tid & 63, w = tid >> 6;
  const int quad = lane >> 4, r16 = lane & 15;
  const int m0 = blockIdx.y * 128, n0 = blockIdx.x * 128;
  const int wm = (w >> 1) * 64, wn = (w & 1) * 64;

  f32x4 acc[4][4] = {};

  const int nchunk = K >> 5;
  const int c0 = tid, c1 = tid + 256;   // 16B chunk ids: chunk c covers row c/4, cols (c%4)*8..+7
  for (int kk = 0; kk < nchunk; ++kk) {
    const int k0 = kk << 5;
    __syncthreads();   // previous compute done before LDS overwrite
    async_load16(A  + ((size_t)(m0 + (c0 >> 2)) * K + k0 + (c0 & 3) * 8), As + (size_t)(w * 64) * 8);
    async_load16(A  + ((size_t)(m0 + (c1 >> 2)) * K + k0 + (c1 & 3) * 8), As + (size_t)(256 + w * 64) * 8);
    async_load16(Bt + ((size_t)(n0 + (c0 >> 2)) * K + k0 + (c0 & 3) * 8), Bs + (size_t)(w * 64) * 8);
    async_load16(Bt + ((size_t)(n0 + (c1 >> 2)) * K + k0 + (c1 & 3) * 8), Bs + (size_t)(256 + w * 64) * 8);
    __syncthreads();   // compiler drains vmcnt before s_barrier
    bf16x8 af[4], bfr[4];
    #pragma unroll
    for (int i = 0; i < 4; ++i)
      af[i] = *(const bf16x8*)(As + ((wm + i * 16 + r16) * 32 + quad * 8));
    #pragma unroll
    for (int j = 0; j < 4; ++j)
      bfr[j] = *(const bf16x8*)(Bs + ((wn + j * 16 + r16) * 32 + quad * 8));
    #pragma unroll
    for (int i = 0; i < 4; ++i)
      #pragma unroll
      for (int j = 0; j < 4; ++j)
        acc[i][j] = __builtin_amdgcn_mfma_f32_16x16x32_bf16(af[i], bfr[j], acc[i][j], 0, 0, 0);
  }

  #pragma unroll
  for (int j = 0; j < 4; ++j) {
    const int col = n0 + wn + j * 16 + r16;
    const float bv = bias ? bias[col] : 0.0f;
    #pragma unroll
    for (int i = 0; i < 4; ++i) {
      #pragma unroll
      for (int r = 0; r < 4; ++r) {
        const int row = m0 + wm + i * 16 + quad * 4 + r;
        float v = acc[i][j][r] + bv;
        if (relu) v = fmaxf(v, 0.0f);
        if (outF) outF[(size_t)row * N + col] = v;
        if (outB) outB[(size_t)row * N + col] = f2bf(v);
      }
    }
  }
}

// ---------------- V transpose (bf16): vt[bh][d][s] = qkv_bf[b,s, 2D + h*64 + d] --------
__global__ void vt_kernel(const unsigned short* __restrict__ qkv, unsigned short* __restrict__ vt) {
  __shared__ unsigned short t[32][34];
  const int bh = blockIdx.z, b = bh >> 3, hh = bh & 7;
  const int s0 = blockIdx.x * 32, d0 = blockIdx.y * 32;
  for (int i = threadIdx.y; i < 32; i += 8)
    t[i][threadIdx.x] = qkv[(size_t)(b * Ss + s0 + i) * 1536 + 1024 + hh * 64 + d0 + threadIdx.x];
  __syncthreads();
  for (int i = threadIdx.y; i < 32; i += 8)
    vt[((size_t)bh * 64 + d0 + i) * Ss + s0 + threadIdx.x] = t[threadIdx.x][i];
}

// ---------------- MFMA flash attention (causal), bf16 in / bf16 out -------------------
// grid (S/64 q-tiles, B*H). 256 threads = 4 waves, each wave owns 16 q-rows.
// Per 64-key tile: stage K[64x64] and Vt[64x64] to LDS (global_load_lds, XOR-swizzled
// global source so swizzled ds_read is conflict-free), QK^T MFMA, wave-parallel online
// softmax, P->bf16 via per-wave swizzled LDS buffer, PV MFMA.
__global__ __launch_bounds__(256) void fattn_kernel(const unsigned short* __restrict__ qkv,
                                                    const unsigned short* __restrict__ vt,
                                                    unsigned short* __restrict__ o) {
  const int qt = blockIdx.x, bh = blockIdx.y;
  const int b = bh >> 3, hh = bh & 7;
  const int tid = threadIdx.x, lane = tid & 63, w = tid >> 6;
  const int quad = lane >> 4, r16 = lane & 15;
  const int q0 = qt * 64;
  const int qw = q0 + w * 16;           // wave's q rows: qw .. qw+15

  __shared__ __align__(16) unsigned short Ks[64 * 64];   // [key][d], 16B-chunk XOR swizzle
  __shared__ __align__(16) unsigned short Vs[64 * 64];   // [d][key], same swizzle
  __shared__ __align__(16) unsigned short Ps[4][16 * 64]; // per-wave P, same swizzle

  // Q fragments (once): A[m=r16][k = kk*32 + quad*8 + j]
  bf16x8 aq[2];
  {
    const unsigned short* qp = qkv + (size_t)(b * Ss + qw + r16) * 1536 + hh * 64 + quad * 8;
    aq[0] = *(const bf16x8*)(qp);
    aq[1] = *(const bf16x8*)(qp + 32);
  }

  f32x4 accO[4] = {};                       // O[q = qw + quad*4 + r][d = jd*16 + r16]
  float mst[4] = {-1e30f, -1e30f, -1e30f, -1e30f};
  float lst[4] = {0.f, 0.f, 0.f, 0.f};

  // staging chunk ids (16B chunks, 8 per 64-elem row): physical (row, p) <- logical (row, p^(row&7))
  const int c0 = tid, c1 = tid + 256;
  const int row0 = c0 >> 3, p0s = (c0 & 7) ^ (row0 & 7);
  const int row1 = c1 >> 3, p1s = (c1 & 7) ^ (row1 & 7);
  const int sw = r16 & 7;

  for (int kt = 0; kt <= qt; ++kt) {
    const int kt0 = kt * 64;
    __syncthreads();   // previous tile's reads done before overwrite
    async_load16(qkv + (size_t)(b * Ss + kt0 + row0) * 1536 + 512 + hh * 64 + (p0s << 3), Ks + w * 512);
    async_load16(qkv + (size_t)(b * Ss + kt0 + row1) * 1536 + 512 + hh * 64 + (p1s << 3), Ks + 2048 + w * 512);
    async_load16(vt + (size_t)(bh * 64 + row0) * Ss + kt0 + (p0s << 3), Vs + w * 512);
    async_load16(vt + (size_t)(bh * 64 + row1) * Ss + kt0 + (p1s << 3), Vs + 2048 + w * 512);
    __syncthreads();   // compiler drains vmcnt before s_barrier

    // S = Q K^T : accS[j][r] = S[q = qw + quad*4 + r][key = kt0 + j*16 + r16_col]
    f32x4 accS[4] = {};
    #pragma unroll
    for (int kk = 0; kk < 2; ++kk) {
      #pragma unroll
      for (int j = 0; j < 4; ++j) {
        const bf16x8 bk = *(const bf16x8*)(Ks + (j * 16 + r16) * 64 + (((kk * 4 + quad) ^ sw) << 3));
        accS[j] = __builtin_amdgcn_mfma_f32_16x16x32_bf16(aq[kk], bk, accS[j], 0, 0, 0);
      }
    }

    if (kt == qt) {   // diagonal tile: mask key_local > q_local
      #pragma unroll
      for (int j = 0; j < 4; ++j)
        #pragma unroll
        for (int r = 0; r < 4; ++r)
          if (j * 16 + r16 > w * 16 + quad * 4 + r) accS[j][r] = -1e30f;
    }

    // row max (raw scores) across j then across the 16-lane column group
    float mx[4];
    #pragma unroll
    for (int r = 0; r < 4; ++r)
      mx[r] = fmaxf(fmaxf(accS[0][r], accS[1][r]), fmaxf(accS[2][r], accS[3][r]));
    #pragma unroll
    for (int msk = 1; msk < 16; msk <<= 1)
      #pragma unroll
      for (int r = 0; r < 4; ++r)
        mx[r] = fmaxf(mx[r], __shfl_xor(mx[r], msk, 64));

    // online-softmax update (m tracked in scaled domain: 0.125 * s)
    float corr[4];
    #pragma unroll
    for (int r = 0; r < 4; ++r) {
      const float mn = fmaxf(mst[r], 0.125f * mx[r]);
      corr[r] = __expf(mst[r] - mn);
      mst[r] = mn;
      lst[r] *= corr[r];
    }
    #pragma unroll
    for (int jd = 0; jd < 4; ++jd)
      #pragma unroll
      for (int r = 0; r < 4; ++r)
        accO[jd][r] *= corr[r];

    // P = exp(0.125*s - m) -> bf16 -> per-wave LDS (swizzled), no cross-wave sync needed
    unsigned short* pw = Ps[w];
    #pragma unroll
    for (int j = 0; j < 4; ++j)
      #pragma unroll
      for (int r = 0; r < 4; ++r) {
        const float p = __expf(fmaf(accS[j][r], 0.125f, -mst[r]));
        lst[r] += p;
        const int prow = quad * 4 + r, pcol = j * 16 + r16;
        pw[prow * 64 + ((((pcol >> 3) ^ (prow & 7)) << 3) | (pcol & 7))] = f2bf(p);
      }

    // O += P @ V : A-frag = P[q=r16][key chunk], B-frag = Vt[d=jd*16+r16][key chunk]
    #pragma unroll
    for (int kk = 0; kk < 2; ++kk) {
      const bf16x8 ap = *(const bf16x8*)(pw + r16 * 64 + (((kk * 4 + quad) ^ sw) << 3));
      #pragma unroll
      for (int jd = 0; jd < 4; ++jd) {
        const bf16x8 bv = *(const bf16x8*)(Vs + (jd * 16 + r16) * 64 + (((kk * 4 + quad) ^ sw) << 3));
        accO[jd] = __builtin_amdgcn_mfma_f32_16x16x32_bf16(ap, bv, accO[jd], 0, 0, 0);
      }
    }
  }

  // finalize: reduce l across the 16-lane column group, normalize, store bf16
  float inv[4];
  #pragma unroll
  for (int r = 0; r < 4; ++r) {
    float s = lst[r];
    #pragma unroll
    for (int msk = 1; msk < 16; msk <<= 1) s += __shfl_xor(s, msk, 64);
    inv[r] = 1.0f / s;
  }
  #pragma unroll
  for (int jd = 0; jd < 4; ++jd)
    #pragma unroll
    for (int r = 0; r < 4; ++r)
      o[(size_t)(b * Ss + qw + quad * 4 + r) * Dd + hh * 64 + jd * 16 + r16] =
          f2bf(accO[jd][r] * inv[r]);
}

// ---------------- LayerNorm (+optional residual add), fp32 + bf16 outputs ------------
__global__ __launch_bounds__(256) void ln_kernel(const float* x, const float* res,
                                                 const float* g, const float* b,
                                                 float* outF, unsigned short* outB) {
  const int row = blockIdx.x, tid = threadIdx.x;
  const size_t base = (size_t)row * Dd;
  float v0 = x[base + tid], v1 = x[base + tid + 256];
  if (res) { v0 += res[base + tid]; v1 += res[base + tid + 256]; }
  __shared__ float s1[256], s2[256];
  s1[tid] = v0 + v1; s2[tid] = v0 * v0 + v1 * v1;
  __syncthreads();
  for (int off = 128; off > 0; off >>= 1) {
    if (tid < off) { s1[tid] += s1[tid + off]; s2[tid] += s2[tid + off]; }
    __syncthreads();
  }
  const float mean = s1[0] * (1.0f / Dd);
  const float var  = s2[0] * (1.0f / Dd) - mean * mean;
  const float rstd = rsqrtf(var + 1e-5f);
  const float o0 = (v0 - mean) * rstd * g[tid] + b[tid];
  const float o1 = (v1 - mean) * rstd * g[tid + 256] + b[tid + 256];
  if (outF) { outF[base + tid] = o0; outF[base + tid + 256] = o1; }
  if (outB) { outB[base + tid] = f2bf(o0); outB[base + tid + 256] = f2bf(o1); }
}

// =====================================================================================
extern "C" void kernel_launch(void* const* d_in, const int* in_sizes, int n_in,
                              void* d_out, int out_size, void* d_ws, size_t ws_size,
                              hipStream_t stream) {
  const int*   x    = (const int*)d_in[0];
  const float* emb  = (const float*)d_in[1];
  const float* pe   = (const float*)d_in[2];
  const float* Wqkv = (const float*)d_in[3];
  const float* Wo   = (const float*)d_in[4];
  const float* bo   = (const float*)d_in[5];
  const float* g1   = (const float*)d_in[6];
  const float* b1   = (const float*)d_in[7];
  const float* g2   = (const float*)d_in[8];
  const float* b2   = (const float*)d_in[9];
  const float* W1   = (const float*)d_in[10];
  const float* bf1  = (const float*)d_in[11];
  const float* W2   = (const float*)d_in[12];
  const float* bf2  = (const float*)d_in[13];
  const float* gfin = (const float*)d_in[14];
  const float* bfin = (const float*)d_in[15];
  const float* Wout = (const float*)d_in[16];
  const float* bfc  = (const float*)d_in[17];
  float* out = (float*)d_out;
  (void)in_sizes; (void)n_in; (void)out_size; (void)ws_size;

  char* wsp = (char*)d_ws;
  size_t off = 0;
  auto take = [&](size_t bytes) -> void* {
    void* p = wsp + off;
    off += (bytes + 255) & ~(size_t)255;
    return p;
  };
  unsigned short* WqkvT  = (unsigned short*)take((size_t)Lx * 3 * Dd * Dd * 2);
  unsigned short* WoT    = (unsigned short*)take((size_t)Lx * Dd * Dd * 2);
  unsigned short* W1T    = (unsigned short*)take((size_t)Lx * Fx * Dd * 2);
  unsigned short* W2T    = (unsigned short*)take((size_t)Lx * Dd * Fx * 2);
  unsigned short* WoutT  = (unsigned short*)take((size_t)Vv * Dd * 2);
  float*          h      = (float*)take((size_t)Mx * Dd * 4);
  unsigned short* h_bf   = (unsigned short*)take((size_t)Mx * Dd * 2);
  unsigned short* qkvbf  = (unsigned short*)take((size_t)Mx * 3 * Dd * 2);
  unsigned short* vtbf   = (unsigned short*)take((size_t)Bx * Hx * DhX * Ss * 2);
  unsigned short* attnbf = (unsigned short*)take((size_t)Mx * Dd * 2);
  float*          obuf   = (float*)take((size_t)Mx * Dd * 4);
  unsigned short* ff1bf  = (unsigned short*)take((size_t)Mx * Fx * 2);
  unsigned short* hfbf   = (unsigned short*)take((size_t)Mx * Dd * 2);

  dim3 tb(32, 8);
  // weight convert+transpose to bf16 [N,K]
  transpose_kernel<<<dim3(3 * Dd / 32, Dd / 32, Lx), tb, 0, stream>>>(Wqkv, WqkvT, Dd, 3 * Dd, (long)Dd * 3 * Dd, (long)3 * Dd * Dd);
  transpose_kernel<<<dim3(Dd / 32, Dd / 32, Lx), tb, 0, stream>>>(Wo, WoT, Dd, Dd, (long)Dd * Dd, (long)Dd * Dd);
  transpose_kernel<<<dim3(Fx / 32, Dd / 32, Lx), tb, 0, stream>>>(W1, W1T, Dd, Fx, (long)Dd * Fx, (long)Fx * Dd);
  transpose_kernel<<<dim3(Dd / 32, Fx / 32, Lx), tb, 0, stream>>>(W2, W2T, Fx, Dd, (long)Fx * Dd, (long)Dd * Fx);
  transpose_kernel<<<dim3(Vv / 32, Dd / 32, 1), tb, 0, stream>>>(Wout, WoutT, Dd, Vv, 0, 0);

  embed_kernel<<<Mx * Dd / 256, 256, 0, stream>>>(x, emb, pe, h, h_bf);

  for (int l = 0; l < Lx; ++l) {
    gemm_kernel<<<dim3(3 * Dd / 128, Mx / 128), 256, 0, stream>>>(h_bf, WqkvT + (size_t)l * 3 * Dd * Dd, nullptr, nullptr, qkvbf, Mx, 3 * Dd, Dd, 0);
    vt_kernel<<<dim3(Ss / 32, DhX / 32, Bx * Hx), tb, 0, stream>>>(qkvbf, vtbf);
    fattn_kernel<<<dim3(Ss / 64, Bx * Hx), 256, 0, stream>>>(qkvbf, vtbf, attnbf);
    gemm_kernel<<<dim3(Dd / 128, Mx / 128), 256, 0, stream>>>(attnbf, WoT + (size_t)l * Dd * Dd, bo + (size_t)l * Dd, obuf, nullptr, Mx, Dd, Dd, 0);
    ln_kernel<<<Mx, 256, 0, stream>>>(h, obuf, g1 + (size_t)l * Dd, b1 + (size_t)l * Dd, h, h_bf);
    gemm_kernel<<<dim3(Fx / 128, Mx / 128), 256, 0, stream>>>(h_bf, W1T + (size_t)l * Fx * Dd, bf1 + (size_t)l * Fx, nullptr, ff1bf, Mx, Fx, Dd, 1);
    gemm_kernel<<<dim3(Dd / 128, Mx / 128), 256, 0, stream>>>(ff1bf, W2T + (size_t)l * Dd * Fx, bf2 + (size_t)l * Dd, obuf, nullptr, Mx, Dd, Fx, 0);
    ln_kernel<<<Mx, 256, 0, stream>>>(h, obuf, g2 + (size_t)l * Dd, b2 + (size_t)l * Dd, h, h_bf);
  }
  ln_kernel<<<Mx, 256, 0, stream>>>(h, nullptr, gfin, bfin, nullptr, hfbf);
  gemm_kernel<<<dim3(Vv / 128, Mx / 128), 256, 0, stream>>>(hfbf, WoutT, bfc, out, nullptr, Mx, Vv, Dd, 0);
}